// Round 7
// baseline (701.392 us; speedup 1.0000x reference)
//
#include <hip/hip_runtime.h>
#include <math.h>

// Problem constants (reference: B,P,NTIME,NLATENT,NSPATIAL = 4,2,16,32,2048)
#define NB 4
#define NP 2
#define NT 16
#define NC 32
#define NX 2048

// ---------------------------------------------------------------------------
// Precompute G[c,e,A,B] = sum_{t,T} enc[e,t,T] * K[t,A,c] * V[T,B,c]
// For layer 1 (cstride==1) there is no c axis: G[e,A,B].
// ---------------------------------------------------------------------------
__global__ void g_precompute(const float* __restrict__ K,
                             const float* __restrict__ V,
                             const float* __restrict__ enc,
                             float* __restrict__ G,
                             int cstride) {
    const int bid = blockIdx.x;
    int e, c;
    if (cstride == 1) { e = bid; c = 0; }
    else              { c = bid >> 4; e = bid & 15; }

    __shared__ float sK[256], sV[256], sE[256], sW[256];
    const int tid = threadIdx.x;
    {
        const int t = tid >> 4, A = tid & 15;
        sK[tid] = K[(t * 16 + A) * cstride + c];
        sV[tid] = V[(t * 16 + A) * cstride + c];
        sE[tid] = enc[(e * 16 + t) * 16 + A];
    }
    __syncthreads();
    {   // W[t,B] = sum_T enc[e,t,T] * V[T,B,c]
        const int t = tid >> 4, Bi = tid & 15;
        float acc = 0.f;
#pragma unroll
        for (int T = 0; T < 16; ++T) acc += sE[t * 16 + T] * sV[T * 16 + Bi];
        sW[tid] = acc;
    }
    __syncthreads();
    {   // G[A,B] = sum_t K[t,A,c] * W[t,B]
        const int A = tid >> 4, Bi = tid & 15;
        float acc = 0.f;
#pragma unroll
        for (int t = 0; t < 16; ++t) acc += sK[t * 16 + A] * sW[t * 16 + Bi];
        G[((c * 16 + e) * 16 + A) * 16 + Bi] = acc;
    }
}

// M1t[e][E][T] = sum_t Q1[t,T] * dec[e,t,E]   (q1 fused; laid out for per-e rows)
__global__ void m1t_precompute(const float* __restrict__ Q1,
                               const float* __restrict__ dec,
                               float* __restrict__ M1t) {
    const int idx = blockIdx.x * 256 + threadIdx.x;  // 4096
    const int e = idx >> 8, E = (idx >> 4) & 15, T = idx & 15;
    float acc = 0.f;
#pragma unroll
    for (int t = 0; t < 16; ++t)
        acc += Q1[t * 16 + T] * dec[(e * 16 + t) * 16 + E];
    M1t[idx] = acc;
}

// M2[c][T][A][E] = sum_t Q0[t,A,c] * dec[E,t,T]  (q0 fused into final stage)
__global__ void m2_precompute(const float* __restrict__ Q0,
                              const float* __restrict__ dec,
                              float* __restrict__ M2) {
    const int idx = blockIdx.x * 256 + threadIdx.x;  // 131072
    const int c = idx >> 12, T = (idx >> 8) & 15, A = (idx >> 4) & 15, E = idx & 15;
    float acc = 0.f;
#pragma unroll
    for (int t = 0; t < 16; ++t)
        acc += Q0[(t * 16 + A) * NC + c] * dec[(E * 16 + t) * 16 + T];
    M2[idx] = acc;
}

__device__ __forceinline__ float sqrt_act(float v) {
    return copysignf(sqrtf(fabsf(v)), v);
}

// dot of one wave-uniform 16-float weight row (global ptr with uniform
// address -> compiler emits s_load_dwordx16; values live in SGPRs, zero
// per-lane replication cost) against FOUR per-thread 16-vectors.
// 8 independent FMA chains; 128 FMA per 64-byte row (256 cyc) covers
// scalar-load latency (~200 cyc) even with shallow lookahead.
__device__ __forceinline__ void dot4(const float* __restrict__ row,
                                     const float (&v0)[16], const float (&v1)[16],
                                     const float (&v2)[16], const float (&v3)[16],
                                     float& s0, float& s1, float& s2, float& s3) {
    float a0 = 0.f, b0 = 0.f, a1 = 0.f, b1 = 0.f;
    float a2 = 0.f, b2 = 0.f, a3 = 0.f, b3 = 0.f;
#pragma unroll
    for (int i = 0; i < 16; i += 2) {
        a0 += row[i] * v0[i];     b0 += row[i + 1] * v0[i + 1];
        a1 += row[i] * v1[i];     b1 += row[i + 1] * v1[i + 1];
        a2 += row[i] * v2[i];     b2 += row[i + 1] * v2[i + 1];
        a3 += row[i] * v3[i];     b3 += row[i + 1] * v3[i + 1];
    }
    s0 = a0 + b0;  s1 = a1 + b1;  s2 = a2 + b2;  s3 = a3 + b3;
}

// ---------------------------------------------------------------------------
// Main kernel: one thread per FOUR (b,p,c,x) sites (x0 + {0,256,512,768}).
// Weights read DIRECTLY from global via wave-uniform addresses -> s_load
// into SGPRs (no LDS staging: LDS broadcast pays full 64-lane datapath
// replication, ~327us at R=2 per the R4/R6 post-mortems; SGPRs are shared
// per-wave so the SMEM path is throughput-free).
// Stages 1+2 fused (p_e consumed immediately; live set = h + b2 only).
// NO min-waves launch bound (R5 lesson); no LDS row buffers (R6 lesson).
// grid = NB*NP*NC*(NX/1024) = 512 blocks of 256 threads = exactly 2/CU.
// bid bits: [0]=x-chunk, [5:1]=c, [8:6]=bp
// ---------------------------------------------------------------------------
__global__ __launch_bounds__(256) void site_kernel(
    const float* __restrict__ x,
    const float* __restrict__ a,
    const float* __restrict__ w,
    const float* __restrict__ G0,
    const float* __restrict__ G1,
    const float* __restrict__ M1t,
    const float* __restrict__ M2,
    float* __restrict__ out) {
    const int tid = threadIdx.x;
    const int bid = blockIdx.x;
    const int xc = bid & 1;
    const int c  = (bid >> 1) & 31;
    const int bp = bid >> 6;              // [0, NB*NP)
    const int x0 = (xc << 10) + tid;      // site s at x0 + s*256
    const float* xb = x + (bp * NT * NC + c) * NX;

    // ---- load all four sites' 16-vectors (coalesced) ----
    float X0[16], X1[16], X2[16], X3[16];
#pragma unroll
    for (int t = 0; t < 16; ++t) {
        X0[t] = xb[t * NC * NX + x0];
        X1[t] = xb[t * NC * NX + x0 + 256];
        X2[t] = xb[t * NC * NX + x0 + 512];
        X3[t] = xb[t * NC * NX + x0 + 768];
    }

    // ======== stage 0: h[e] = sqrt_act( X^T G0[c,e] X ) ========
    float h0[16], h1[16], h2[16], h3[16];
    {
        const float* G0c = G0 + c * 4096;
#pragma unroll 1
        for (int e = 0; e < 16; ++e) {
            const float* g = G0c + e * 256;
            float c0 = 0.f, d0 = 0.f, c1 = 0.f, d1 = 0.f;
            float c2 = 0.f, d2 = 0.f, c3 = 0.f, d3 = 0.f;
#pragma unroll
            for (int A = 0; A < 16; ++A) {
                float s0, s1, s2, s3;
                dot4(g + A * 16, X0, X1, X2, X3, s0, s1, s2, s3);
                if (A & 1) { d0 += X0[A] * s0; d1 += X1[A] * s1;
                             d2 += X2[A] * s2; d3 += X3[A] * s3; }
                else       { c0 += X0[A] * s0; c1 += X1[A] * s1;
                             c2 += X2[A] * s2; c3 += X3[A] * s3; }
            }
            h0[e] = sqrt_act(c0 + d0);
            h1[e] = sqrt_act(c1 + d1);
            h2[e] = sqrt_act(c2 + d2);
            h3[e] = sqrt_act(c3 + d3);
        }
    }
    // X dead here (re-loaded for the final stage).

    // ======== stages 1+2 fused:
    //   p_e = a[e,x] * sqrt_act( h^T G1[e] h )
    //   b2[E] += p_e * ( sum_T h_T * M1t[e,E,T] )      (p never materialized)
    float b20[16], b21[16], b22[16], b23[16];
#pragma unroll
    for (int E = 0; E < 16; ++E) { b20[E] = 0.f; b21[E] = 0.f;
                                   b22[E] = 0.f; b23[E] = 0.f; }
    {
#pragma unroll 1
        for (int e = 0; e < 16; ++e) {
            const float ae0 = a[e * NX + x0];
            const float ae1 = a[e * NX + x0 + 256];
            const float ae2 = a[e * NX + x0 + 512];
            const float ae3 = a[e * NX + x0 + 768];
            const float* g = G1 + e * 256;
            float c0 = 0.f, d0 = 0.f, c1 = 0.f, d1 = 0.f;
            float c2 = 0.f, d2 = 0.f, c3 = 0.f, d3 = 0.f;
#pragma unroll
            for (int A = 0; A < 16; ++A) {
                float s0, s1, s2, s3;
                dot4(g + A * 16, h0, h1, h2, h3, s0, s1, s2, s3);
                if (A & 1) { d0 += h0[A] * s0; d1 += h1[A] * s1;
                             d2 += h2[A] * s2; d3 += h3[A] * s3; }
                else       { c0 += h0[A] * s0; c1 += h1[A] * s1;
                             c2 += h2[A] * s2; c3 += h3[A] * s3; }
            }
            const float pe0 = ae0 * sqrt_act(c0 + d0);
            const float pe1 = ae1 * sqrt_act(c1 + d1);
            const float pe2 = ae2 * sqrt_act(c2 + d2);
            const float pe3 = ae3 * sqrt_act(c3 + d3);
            const float* m = M1t + e * 256;
#pragma unroll
            for (int E = 0; E < 16; ++E) {
                float s0, s1, s2, s3;
                dot4(m + E * 16, h0, h1, h2, h3, s0, s1, s2, s3);
                b20[E] += pe0 * s0;
                b21[E] += pe1 * s1;
                b22[E] += pe2 * s2;
                b23[E] += pe3 * s3;
            }
        }
    }
    // h dead here.

    // ---- memory fence: stop the compiler hoisting the Y reload above the
    // fused stage (the R6 live-range blow-up), and keep X truly dead ----
    asm volatile("" ::: "memory");
    const float* xr = xb;
    asm volatile("" : "+r"(xr));
    float Y0[16], Y1[16], Y2[16], Y3[16];
#pragma unroll
    for (int t = 0; t < 16; ++t) {
        Y0[t] = xr[t * NC * NX + x0];
        Y1[t] = xr[t * NC * NX + x0 + 256];
        Y2[t] = xr[t * NC * NX + x0 + 512];
        Y3[t] = xr[t * NC * NX + x0 + 768];
    }

    // ======== stage 3: y = sum_T w[T,x] * ( Y^T M2[c,T] b2 ) ========
    float y0 = 0.f, y1 = 0.f, y2 = 0.f, y3 = 0.f;
    {
        const float* M2c = M2 + c * 4096;
#pragma unroll 1
        for (int T = 0; T < 16; ++T) {
            const float wt0 = w[T * NX + x0];
            const float wt1 = w[T * NX + x0 + 256];
            const float wt2 = w[T * NX + x0 + 512];
            const float wt3 = w[T * NX + x0 + 768];
            const float* m = M2c + T * 256;
            float c0 = 0.f, d0 = 0.f, c1 = 0.f, d1 = 0.f;
            float c2 = 0.f, d2 = 0.f, c3 = 0.f, d3 = 0.f;
#pragma unroll
            for (int A = 0; A < 16; ++A) {
                float s0, s1, s2, s3;
                dot4(m + A * 16, b20, b21, b22, b23, s0, s1, s2, s3);
                if (A & 1) { d0 += Y0[A] * s0; d1 += Y1[A] * s1;
                             d2 += Y2[A] * s2; d3 += Y3[A] * s3; }
                else       { c0 += Y0[A] * s0; c1 += Y1[A] * s1;
                             c2 += Y2[A] * s2; c3 += Y3[A] * s3; }
            }
            y0 += wt0 * (c0 + d0);
            y1 += wt1 * (c1 + d1);
            y2 += wt2 * (c2 + d2);
            y3 += wt3 * (c3 + d3);
        }
    }

    // ---- reduce over the block, one atomic per block ----
    float y = (y0 + y1) + (y2 + y3);
#pragma unroll
    for (int off = 32; off > 0; off >>= 1) y += __shfl_down(y, off);
    __shared__ float red[4];
    if ((tid & 63) == 0) red[tid >> 6] = y;
    __syncthreads();
    if (tid == 0) {
        atomicAdd(&out[bp * NC + c], red[0] + red[1] + red[2] + red[3]);
    }
}

extern "C" void kernel_launch(void* const* d_in, const int* in_sizes, int n_in,
                              void* d_out, int out_size, void* d_ws, size_t ws_size,
                              hipStream_t stream) {
    const float* x   = (const float*)d_in[0];
    const float* K0  = (const float*)d_in[1];
    const float* Q0  = (const float*)d_in[2];
    const float* V0  = (const float*)d_in[3];
    const float* K1  = (const float*)d_in[4];
    const float* Q1  = (const float*)d_in[5];
    const float* V1  = (const float*)d_in[6];
    const float* enc = (const float*)d_in[7];
    const float* dec = (const float*)d_in[8];
    const float* a   = (const float*)d_in[9];
    const float* w   = (const float*)d_in[10];
    float* out = (float*)d_out;

    float* G0  = (float*)d_ws;       // 32*4096 = 131072 floats
    float* G1  = G0 + NC * 4096;     // 4096
    float* M1t = G1 + 4096;          // 4096
    float* M2  = M1t + 4096;         // 131072
    // total ws: 270336 floats ~= 1.06 MB

    // out must be zeroed every call (harness re-poisons with 0xAA)
    hipMemsetAsync(d_out, 0, (size_t)out_size * sizeof(float), stream);

    g_precompute<<<NC * 16, 256, 0, stream>>>(K0, V0, enc, G0, NC);
    g_precompute<<<16,      256, 0, stream>>>(K1, V1, enc, G1, 1);
    m1t_precompute<<<16,  256, 0, stream>>>(Q1, dec, M1t);
    m2_precompute<<<512, 256, 0, stream>>>(Q0, dec, M2);

    const int nblocks = NB * NP * NC * (NX / 1024);  // 512
    site_kernel<<<nblocks, 256, 0, stream>>>(x, a, w, G0, G1, M1t, M2, out);
}

// Round 8
// 370.571 us; speedup vs baseline: 1.8927x; 1.8927x over previous
//
#include <hip/hip_runtime.h>
#include <math.h>

// Problem constants (reference: B,P,NTIME,NLATENT,NSPATIAL = 4,2,16,32,2048)
#define NB 4
#define NP 2
#define NT 16
#define NC 32
#define NX 2048

// Triangle packing: symmetric bilinear form weights packed per e as rows
// A=0..15, row A holds S[A,j]: S[A,0]=G[A,A], S[A,j]=G[A,A+j]+G[A+j,A],
// padded to P(A)=((16-A)+3)&~3 floats (pad=0). Total 160 floats per e.
__device__ __host__ constexpr int tri_pad(int A) { return ((16 - A) + 3) & ~3; }
#define TRI_TOTAL 160

// ---------------------------------------------------------------------------
// Precompute packed-symmetric G for the bilinear stages:
//   G[A,B] = sum_{t,T} enc[e,t,T] * K[t,A,c] * V[T,B,c]   -> packed S rows.
// One block per (c,e); cstride==1 => layer 1 (no c axis).
// ---------------------------------------------------------------------------
__global__ void g_precompute(const float* __restrict__ K,
                             const float* __restrict__ V,
                             const float* __restrict__ enc,
                             float* __restrict__ Gp,
                             int cstride) {
    const int bid = blockIdx.x;
    int e, c;
    if (cstride == 1) { e = bid; c = 0; }
    else              { c = bid >> 4; e = bid & 15; }

    __shared__ float sK[256], sV[256], sE[256], sW[256];
    const int tid = threadIdx.x;
    {
        const int t = tid >> 4, A = tid & 15;
        sK[tid] = K[(t * 16 + A) * cstride + c];
        sV[tid] = V[(t * 16 + A) * cstride + c];
        sE[tid] = enc[(e * 16 + t) * 16 + A];
    }
    __syncthreads();
    {   // W[t,B] = sum_T enc[e,t,T] * V[T,B,c]
        const int t = tid >> 4, Bi = tid & 15;
        float acc = 0.f;
#pragma unroll
        for (int T = 0; T < 16; ++T) acc += sE[t * 16 + T] * sV[T * 16 + Bi];
        sW[tid] = acc;
    }
    __syncthreads();
    float gval;
    {   // G[A,B] = sum_t K[t,A,c] * W[t,B]
        const int A = tid >> 4, Bi = tid & 15;
        float acc = 0.f;
#pragma unroll
        for (int t = 0; t < 16; ++t) acc += sK[t * 16 + A] * sW[t * 16 + Bi];
        gval = acc;
    }
    __syncthreads();           // sE reads (step 1) done everywhere
    sE[tid] = gval;            // sE := full G tile
    __syncthreads();
    // pack upper triangle (+ transposed lower) into padded rows
    if (tid < TRI_TOTAL) {
        int A = 0, off = 0;
        while (A < 15 && tid >= off + tri_pad(A)) { off += tri_pad(A); ++A; }
        const int j = tid - off;
        const int L = 16 - A;
        float v = 0.f;
        if (j < L) v = (j == 0) ? sE[A * 16 + A]
                                : sE[A * 16 + A + j] + sE[(A + j) * 16 + A];
        Gp[(c * 16 + e) * TRI_TOTAL + tid] = v;
    }
}

// M1t[e][E][T] = sum_t Q1[t,T] * dec[e,t,E]   (q1 fused; per-e rect rows)
__global__ void m1t_precompute(const float* __restrict__ Q1,
                               const float* __restrict__ dec,
                               float* __restrict__ M1t) {
    const int idx = blockIdx.x * 256 + threadIdx.x;  // 4096
    const int e = idx >> 8, E = (idx >> 4) & 15, T = idx & 15;
    float acc = 0.f;
#pragma unroll
    for (int t = 0; t < 16; ++t)
        acc += Q1[t * 16 + T] * dec[(e * 16 + t) * 16 + E];
    M1t[idx] = acc;
}

// M2[c][T][A][E] = sum_t Q0[t,A,c] * dec[E,t,T]  (q0 fused into final stage)
__global__ void m2_precompute(const float* __restrict__ Q0,
                              const float* __restrict__ dec,
                              float* __restrict__ M2) {
    const int idx = blockIdx.x * 256 + threadIdx.x;  // 131072
    const int c = idx >> 12, T = (idx >> 8) & 15, A = (idx >> 4) & 15, E = idx & 15;
    float acc = 0.f;
#pragma unroll
    for (int t = 0; t < 16; ++t)
        acc += Q0[(t * 16 + A) * NC + c] * dec[(E * 16 + t) * 16 + T];
    M2[idx] = acc;
}

__device__ __forceinline__ float sqrt_act(float v) {
    return copysignf(sqrtf(fabsf(v)), v);
}

// rect dot: one 16-float LDS row (wave-uniform broadcast) x FOUR site vectors
__device__ __forceinline__ void dot4(const float* __restrict__ row,
                                     const float (&v0)[16], const float (&v1)[16],
                                     const float (&v2)[16], const float (&v3)[16],
                                     float& s0, float& s1, float& s2, float& s3) {
    float a0 = 0.f, b0 = 0.f, a1 = 0.f, b1 = 0.f;
    float a2 = 0.f, b2 = 0.f, a3 = 0.f, b3 = 0.f;
#pragma unroll
    for (int i = 0; i < 16; i += 2) {
        a0 += row[i] * v0[i];     b0 += row[i + 1] * v0[i + 1];
        a1 += row[i] * v1[i];     b1 += row[i + 1] * v1[i + 1];
        a2 += row[i] * v2[i];     b2 += row[i + 1] * v2[i + 1];
        a3 += row[i] * v3[i];     b3 += row[i + 1] * v3[i + 1];
    }
    s0 = a0 + b0;  s1 = a1 + b1;  s2 = a2 + b2;  s3 = a3 + b3;
}

// triangular bilinear form for four sites: acc_s = V_s^T Sym(G) V_s using
// packed rows (160 floats). Pad weights are 0 so clamped index is safe.
#define TRIFORM(SG, V0, V1, V2, V3, R0, R1, R2, R3)                        \
    do {                                                                   \
        float t_c0 = 0.f, t_d0 = 0.f, t_c1 = 0.f, t_d1 = 0.f;              \
        float t_c2 = 0.f, t_d2 = 0.f, t_c3 = 0.f, t_d3 = 0.f;              \
        int t_off = 0;                                                     \
        _Pragma("unroll")                                                  \
        for (int A = 0; A < 16; ++A) {                                     \
            const int P = tri_pad(A);                                      \
            float t_a0 = 0.f, t_a1 = 0.f, t_a2 = 0.f, t_a3 = 0.f;          \
            _Pragma("unroll")                                              \
            for (int j = 0; j < P; ++j) {                                  \
                const int Bq = (A + j > 15) ? 15 : (A + j);                \
                const float rw = (SG)[t_off + j];                          \
                t_a0 += rw * V0[Bq];  t_a1 += rw * V1[Bq];                 \
                t_a2 += rw * V2[Bq];  t_a3 += rw * V3[Bq];                 \
            }                                                              \
            if (A & 1) { t_d0 += V0[A] * t_a0; t_d1 += V1[A] * t_a1;       \
                         t_d2 += V2[A] * t_a2; t_d3 += V3[A] * t_a3; }     \
            else       { t_c0 += V0[A] * t_a0; t_c1 += V1[A] * t_a1;       \
                         t_c2 += V2[A] * t_a2; t_c3 += V3[A] * t_a3; }     \
            t_off += P;                                                    \
        }                                                                  \
        R0 = t_c0 + t_d0;  R1 = t_c1 + t_d1;                               \
        R2 = t_c2 + t_d2;  R3 = t_c3 + t_d3;                               \
    } while (0)

__device__ __forceinline__ void fill_lds(float* dst, const float* src,
                                         int n4, int tid) {
    const float4* s4 = (const float4*)src;
    float4* d4 = (float4*)dst;
    for (int i = tid; i < n4; i += 256) d4[i] = s4[i];
}

// ---------------------------------------------------------------------------
// Main kernel: one thread per FOUR (b,p,c,x) sites (x0 + {0,256,512,768}).
// Weights staged in LDS (wave-uniform broadcast reads). R=4 amortizes the
// LDS 64-lane replication cost (binding pipe: ~133us at R=4 vs 327 at R=2).
// Bilinear stages use packed-symmetric triangle rows (-37.5% of their
// LDS bytes & FLOPs). Stages 1+2 fused. Memory fence before Y reload
// (R7 lesson: prevents CSE keeping X alive -> was the R6 spill).
// grid = NB*NP*NC*(NX/1024) = 512 blocks of 256 = exactly 2/CU.
// ---------------------------------------------------------------------------
__global__ __launch_bounds__(256) void site_kernel(
    const float* __restrict__ x,
    const float* __restrict__ a,
    const float* __restrict__ w,
    const float* __restrict__ G0p,
    const float* __restrict__ G1p,
    const float* __restrict__ M1t,
    const float* __restrict__ M2,
    float* __restrict__ out) {
    const int tid = threadIdx.x;
    const int bid = blockIdx.x;
    const int xc = bid & 1;
    const int c  = (bid >> 1) & 31;
    const int bp = bid >> 6;              // [0, NB*NP)
    const int x0 = (xc << 10) + tid;      // site s at x0 + s*256
    const float* xb = x + (bp * NT * NC + c) * NX;

    __shared__ float sw[6656];            // 26 KB staged weights

    // ---- load all four sites' 16-vectors (coalesced) ----
    float X0[16], X1[16], X2[16], X3[16];
#pragma unroll
    for (int t = 0; t < 16; ++t) {
        X0[t] = xb[t * NC * NX + x0];
        X1[t] = xb[t * NC * NX + x0 + 256];
        X2[t] = xb[t * NC * NX + x0 + 512];
        X3[t] = xb[t * NC * NX + x0 + 768];
    }

    // ======== stage 0: h[e] = sqrt_act( X^T Sym(G0[c,e]) X ) ========
    fill_lds(sw, G0p + c * (16 * TRI_TOTAL), (16 * TRI_TOTAL) / 4, tid);
    __syncthreads();
    float h0[16], h1[16], h2[16], h3[16];
    {
#pragma unroll 1
        for (int e = 0; e < 16; ++e) {
            const float* sg = sw + e * TRI_TOTAL;
            float r0, r1, r2, r3;
            TRIFORM(sg, X0, X1, X2, X3, r0, r1, r2, r3);
            h0[e] = sqrt_act(r0);
            h1[e] = sqrt_act(r1);
            h2[e] = sqrt_act(r2);
            h3[e] = sqrt_act(r3);
        }
    }
    // X dead here (re-loaded for the final stage).

    // ======== stages 1+2 fused:
    //   p_e = a[e,x] * sqrt_act( h^T Sym(G1[e]) h )
    //   b2[E] += p_e * ( sum_T h_T * M1t[e,E,T] )
    __syncthreads();
    fill_lds(sw, G1p, (16 * TRI_TOTAL) / 4, tid);          // [0, 2560)
    fill_lds(sw + 16 * TRI_TOTAL, M1t, 4096 / 4, tid);     // [2560, 6656)
    __syncthreads();
    float b20[16], b21[16], b22[16], b23[16];
#pragma unroll
    for (int E = 0; E < 16; ++E) { b20[E] = 0.f; b21[E] = 0.f;
                                   b22[E] = 0.f; b23[E] = 0.f; }
    {
#pragma unroll 1
        for (int e = 0; e < 16; ++e) {
            const float ae0 = a[e * NX + x0];
            const float ae1 = a[e * NX + x0 + 256];
            const float ae2 = a[e * NX + x0 + 512];
            const float ae3 = a[e * NX + x0 + 768];
            const float* sg = sw + e * TRI_TOTAL;
            float r0, r1, r2, r3;
            TRIFORM(sg, h0, h1, h2, h3, r0, r1, r2, r3);
            const float pe0 = ae0 * sqrt_act(r0);
            const float pe1 = ae1 * sqrt_act(r1);
            const float pe2 = ae2 * sqrt_act(r2);
            const float pe3 = ae3 * sqrt_act(r3);
            const float* m = sw + 16 * TRI_TOTAL + e * 256;
#pragma unroll
            for (int E = 0; E < 16; ++E) {
                float s0, s1, s2, s3;
                dot4(m + E * 16, h0, h1, h2, h3, s0, s1, s2, s3);
                b20[E] += pe0 * s0;
                b21[E] += pe1 * s1;
                b22[E] += pe2 * s2;
                b23[E] += pe3 * s3;
            }
        }
    }
    // h dead here.

    // ---- memory fence: stop Y-reload CSE keeping X alive (R6 spill cause) ----
    asm volatile("" ::: "memory");
    const float* xr = xb;
    asm volatile("" : "+r"(xr));
    float Y0[16], Y1[16], Y2[16], Y3[16];
#pragma unroll
    for (int t = 0; t < 16; ++t) {
        Y0[t] = xr[t * NC * NX + x0];
        Y1[t] = xr[t * NC * NX + x0 + 256];
        Y2[t] = xr[t * NC * NX + x0 + 512];
        Y3[t] = xr[t * NC * NX + x0 + 768];
    }

    // ======== stage 3: y = sum_T w[T,x] * ( Y^T M2[c,T] b2 ) ========
    __syncthreads();
    fill_lds(sw, M2 + c * 4096, 4096 / 4, tid);
    __syncthreads();
    float y0 = 0.f, y1 = 0.f, y2 = 0.f, y3 = 0.f;
    {
#pragma unroll 1
        for (int T = 0; T < 16; ++T) {
            const float wt0 = w[T * NX + x0];
            const float wt1 = w[T * NX + x0 + 256];
            const float wt2 = w[T * NX + x0 + 512];
            const float wt3 = w[T * NX + x0 + 768];
            const float* m = sw + T * 256;
            float c0 = 0.f, d0 = 0.f, c1 = 0.f, d1 = 0.f;
            float c2 = 0.f, d2 = 0.f, c3 = 0.f, d3 = 0.f;
#pragma unroll
            for (int A = 0; A < 16; ++A) {
                float s0, s1, s2, s3;
                dot4(m + A * 16, b20, b21, b22, b23, s0, s1, s2, s3);
                if (A & 1) { d0 += Y0[A] * s0; d1 += Y1[A] * s1;
                             d2 += Y2[A] * s2; d3 += Y3[A] * s3; }
                else       { c0 += Y0[A] * s0; c1 += Y1[A] * s1;
                             c2 += Y2[A] * s2; c3 += Y3[A] * s3; }
            }
            y0 += wt0 * (c0 + d0);
            y1 += wt1 * (c1 + d1);
            y2 += wt2 * (c2 + d2);
            y3 += wt3 * (c3 + d3);
        }
    }

    // ---- reduce over the block, one atomic per block ----
    float y = (y0 + y1) + (y2 + y3);
#pragma unroll
    for (int off = 32; off > 0; off >>= 1) y += __shfl_down(y, off);
    __shared__ float red[4];
    if ((tid & 63) == 0) red[tid >> 6] = y;
    __syncthreads();
    if (tid == 0) {
        atomicAdd(&out[bp * NC + c], red[0] + red[1] + red[2] + red[3]);
    }
}

extern "C" void kernel_launch(void* const* d_in, const int* in_sizes, int n_in,
                              void* d_out, int out_size, void* d_ws, size_t ws_size,
                              hipStream_t stream) {
    const float* x   = (const float*)d_in[0];
    const float* K0  = (const float*)d_in[1];
    const float* Q0  = (const float*)d_in[2];
    const float* V0  = (const float*)d_in[3];
    const float* K1  = (const float*)d_in[4];
    const float* Q1  = (const float*)d_in[5];
    const float* V1  = (const float*)d_in[6];
    const float* enc = (const float*)d_in[7];
    const float* dec = (const float*)d_in[8];
    const float* a   = (const float*)d_in[9];
    const float* w   = (const float*)d_in[10];
    float* out = (float*)d_out;

    float* G0p = (float*)d_ws;                 // 32*16*160 = 81920 floats
    float* G1p = G0p + NC * 16 * TRI_TOTAL;    // 16*160 = 2560
    float* M1t = G1p + 16 * TRI_TOTAL;         // 4096
    float* M2  = M1t + 4096;                   // 131072
    // total ws: 219648 floats ~= 0.86 MB

    // out must be zeroed every call (harness re-poisons with 0xAA)
    hipMemsetAsync(d_out, 0, (size_t)out_size * sizeof(float), stream);

    g_precompute<<<NC * 16, 256, 0, stream>>>(K0, V0, enc, G0p, NC);
    g_precompute<<<16,      256, 0, stream>>>(K1, V1, enc, G1p, 1);
    m1t_precompute<<<16,  256, 0, stream>>>(Q1, dec, M1t);
    m2_precompute<<<512, 256, 0, stream>>>(Q0, dec, M2);

    const int nblocks = NB * NP * NC * (NX / 1024);  // 512
    site_kernel<<<nblocks, 256, 0, stream>>>(x, a, w, G0p, G1p, M1t, M2, out);
}

// Round 9
// 352.543 us; speedup vs baseline: 1.9895x; 1.0511x over previous
//
#include <hip/hip_runtime.h>
#include <math.h>

// Problem constants (reference: B,P,NTIME,NLATENT,NSPATIAL = 4,2,16,32,2048)
#define NB 4
#define NP 2
#define NT 16
#define NC 32
#define NX 2048

// Triangle packing: symmetric bilinear form weights packed per e as rows
// A=0..15, row A holds S[A,j]: S[A,0]=G[A,A], S[A,j]=G[A,A+j]+G[A+j,A],
// padded to P(A)=((16-A)+3)&~3 floats (pad=0). Total 160 floats per e.
__device__ __host__ constexpr int tri_pad(int A) { return ((16 - A) + 3) & ~3; }
#define TRI_TOTAL 160

// ---------------------------------------------------------------------------
// Precompute packed-symmetric G for the bilinear stages:
//   G[A,B] = sum_{t,T} enc[e,t,T] * K[t,A,c] * V[T,B,c]   -> packed S rows.
// One block per (c,e); cstride==1 => layer 1 (no c axis).
// ---------------------------------------------------------------------------
__global__ void g_precompute(const float* __restrict__ K,
                             const float* __restrict__ V,
                             const float* __restrict__ enc,
                             float* __restrict__ Gp,
                             int cstride) {
    const int bid = blockIdx.x;
    int e, c;
    if (cstride == 1) { e = bid; c = 0; }
    else              { c = bid >> 4; e = bid & 15; }

    __shared__ float sK[256], sV[256], sE[256], sW[256];
    const int tid = threadIdx.x;
    {
        const int t = tid >> 4, A = tid & 15;
        sK[tid] = K[(t * 16 + A) * cstride + c];
        sV[tid] = V[(t * 16 + A) * cstride + c];
        sE[tid] = enc[(e * 16 + t) * 16 + A];
    }
    __syncthreads();
    {   // W[t,B] = sum_T enc[e,t,T] * V[T,B,c]
        const int t = tid >> 4, Bi = tid & 15;
        float acc = 0.f;
#pragma unroll
        for (int T = 0; T < 16; ++T) acc += sE[t * 16 + T] * sV[T * 16 + Bi];
        sW[tid] = acc;
    }
    __syncthreads();
    float gval;
    {   // G[A,B] = sum_t K[t,A,c] * W[t,B]
        const int A = tid >> 4, Bi = tid & 15;
        float acc = 0.f;
#pragma unroll
        for (int t = 0; t < 16; ++t) acc += sK[t * 16 + A] * sW[t * 16 + Bi];
        gval = acc;
    }
    __syncthreads();           // sE reads (step 1) done everywhere
    sE[tid] = gval;            // sE := full G tile
    __syncthreads();
    // pack upper triangle (+ transposed lower) into padded rows
    if (tid < TRI_TOTAL) {
        int A = 0, off = 0;
        while (A < 15 && tid >= off + tri_pad(A)) { off += tri_pad(A); ++A; }
        const int j = tid - off;
        const int L = 16 - A;
        float v = 0.f;
        if (j < L) v = (j == 0) ? sE[A * 16 + A]
                                : sE[A * 16 + A + j] + sE[(A + j) * 16 + A];
        Gp[(c * 16 + e) * TRI_TOTAL + tid] = v;
    }
}

// M1t[e][E][T] = sum_t Q1[t,T] * dec[e,t,E]   (q1 fused; per-e rect rows)
__global__ void m1t_precompute(const float* __restrict__ Q1,
                               const float* __restrict__ dec,
                               float* __restrict__ M1t) {
    const int idx = blockIdx.x * 256 + threadIdx.x;  // 4096
    const int e = idx >> 8, E = (idx >> 4) & 15, T = idx & 15;
    float acc = 0.f;
#pragma unroll
    for (int t = 0; t < 16; ++t)
        acc += Q1[t * 16 + T] * dec[(e * 16 + t) * 16 + E];
    M1t[idx] = acc;
}

// M2[c][T][A][E] = sum_t Q0[t,A,c] * dec[E,t,T]  (q0 fused into final stage)
__global__ void m2_precompute(const float* __restrict__ Q0,
                              const float* __restrict__ dec,
                              float* __restrict__ M2) {
    const int idx = blockIdx.x * 256 + threadIdx.x;  // 131072
    const int c = idx >> 12, T = (idx >> 8) & 15, A = (idx >> 4) & 15, E = idx & 15;
    float acc = 0.f;
#pragma unroll
    for (int t = 0; t < 16; ++t)
        acc += Q0[(t * 16 + A) * NC + c] * dec[(E * 16 + t) * 16 + T];
    M2[idx] = acc;
}

__device__ __forceinline__ float sqrt_act(float v) {
    return copysignf(sqrtf(fabsf(v)), v);
}

// rect dot: one 16-float LDS row (wave-uniform broadcast) x FOUR site vectors
__device__ __forceinline__ void dot4(const float* __restrict__ row,
                                     const float (&v0)[16], const float (&v1)[16],
                                     const float (&v2)[16], const float (&v3)[16],
                                     float& s0, float& s1, float& s2, float& s3) {
    float a0 = 0.f, b0 = 0.f, a1 = 0.f, b1 = 0.f;
    float a2 = 0.f, b2 = 0.f, a3 = 0.f, b3 = 0.f;
#pragma unroll
    for (int i = 0; i < 16; i += 2) {
        a0 += row[i] * v0[i];     b0 += row[i + 1] * v0[i + 1];
        a1 += row[i] * v1[i];     b1 += row[i + 1] * v1[i + 1];
        a2 += row[i] * v2[i];     b2 += row[i + 1] * v2[i + 1];
        a3 += row[i] * v3[i];     b3 += row[i + 1] * v3[i + 1];
    }
    s0 = a0 + b0;  s1 = a1 + b1;  s2 = a2 + b2;  s3 = a3 + b3;
}

// triangular bilinear form for four sites: acc_s = V_s^T Sym(G) V_s using
// packed rows (160 floats). Pad weights are 0 so clamped index is safe.
#define TRIFORM(SG, V0, V1, V2, V3, R0, R1, R2, R3)                        \
    do {                                                                   \
        float t_c0 = 0.f, t_d0 = 0.f, t_c1 = 0.f, t_d1 = 0.f;              \
        float t_c2 = 0.f, t_d2 = 0.f, t_c3 = 0.f, t_d3 = 0.f;              \
        int t_off = 0;                                                     \
        _Pragma("unroll")                                                  \
        for (int A = 0; A < 16; ++A) {                                     \
            const int P = tri_pad(A);                                      \
            float t_a0 = 0.f, t_a1 = 0.f, t_a2 = 0.f, t_a3 = 0.f;          \
            _Pragma("unroll")                                              \
            for (int j = 0; j < P; ++j) {                                  \
                const int Bq = (A + j > 15) ? 15 : (A + j);                \
                const float rw = (SG)[t_off + j];                          \
                t_a0 += rw * V0[Bq];  t_a1 += rw * V1[Bq];                 \
                t_a2 += rw * V2[Bq];  t_a3 += rw * V3[Bq];                 \
            }                                                              \
            if (A & 1) { t_d0 += V0[A] * t_a0; t_d1 += V1[A] * t_a1;       \
                         t_d2 += V2[A] * t_a2; t_d3 += V3[A] * t_a3; }     \
            else       { t_c0 += V0[A] * t_a0; t_c1 += V1[A] * t_a1;       \
                         t_c2 += V2[A] * t_a2; t_c3 += V3[A] * t_a3; }     \
            t_off += P;                                                    \
        }                                                                  \
        R0 = t_c0 + t_d0;  R1 = t_c1 + t_d1;                               \
        R2 = t_c2 + t_d2;  R3 = t_c3 + t_d3;                               \
    } while (0)

__device__ __forceinline__ void fill_lds(float* dst, const float* src,
                                         int n4, int tid) {
    const float4* s4 = (const float4*)src;
    float4* d4 = (float4*)dst;
    for (int i = tid; i < n4; i += 256) d4[i] = s4[i];
}

// ---------------------------------------------------------------------------
// Main kernel: one thread per FOUR (b,p,c,x) sites (x0 + {0,256,512,768}).
// Weights staged in LDS (wave-uniform broadcast reads). R=4 amortizes the
// LDS 64-lane replication cost. Triangle-packed bilinear stages.
// R8 post-mortem: latency-bound at 2 waves/SIMD (LDS pipe 43%, VALU 31%),
// so this round unrolls the OUTER stage loops by 2 to double in-flight
// ds_reads + independent FMA chains per wave (ILP substitutes for TLP).
// grid = NB*NP*NC*(NX/1024) = 512 blocks of 256 = exactly 2/CU.
// ---------------------------------------------------------------------------
__global__ __launch_bounds__(256) void site_kernel(
    const float* __restrict__ x,
    const float* __restrict__ a,
    const float* __restrict__ w,
    const float* __restrict__ G0p,
    const float* __restrict__ G1p,
    const float* __restrict__ M1t,
    const float* __restrict__ M2,
    float* __restrict__ out) {
    const int tid = threadIdx.x;
    const int bid = blockIdx.x;
    const int xc = bid & 1;
    const int c  = (bid >> 1) & 31;
    const int bp = bid >> 6;              // [0, NB*NP)
    const int x0 = (xc << 10) + tid;      // site s at x0 + s*256
    const float* xb = x + (bp * NT * NC + c) * NX;

    __shared__ float sw[6656];            // 26 KB staged weights

    // ---- load all four sites' 16-vectors (coalesced) ----
    float X0[16], X1[16], X2[16], X3[16];
#pragma unroll
    for (int t = 0; t < 16; ++t) {
        X0[t] = xb[t * NC * NX + x0];
        X1[t] = xb[t * NC * NX + x0 + 256];
        X2[t] = xb[t * NC * NX + x0 + 512];
        X3[t] = xb[t * NC * NX + x0 + 768];
    }

    // ======== stage 0: h[e] = sqrt_act( X^T Sym(G0[c,e]) X ) ========
    fill_lds(sw, G0p + c * (16 * TRI_TOTAL), (16 * TRI_TOTAL) / 4, tid);
    __syncthreads();
    float h0[16], h1[16], h2[16], h3[16];
    {
#pragma unroll 2
        for (int e = 0; e < 16; ++e) {
            const float* sg = sw + e * TRI_TOTAL;
            float r0, r1, r2, r3;
            TRIFORM(sg, X0, X1, X2, X3, r0, r1, r2, r3);
            h0[e] = sqrt_act(r0);
            h1[e] = sqrt_act(r1);
            h2[e] = sqrt_act(r2);
            h3[e] = sqrt_act(r3);
        }
    }
    // X dead here (re-loaded for the final stage).

    // ======== stages 1+2 fused:
    //   p_e = a[e,x] * sqrt_act( h^T Sym(G1[e]) h )
    //   b2[E] += p_e * ( sum_T h_T * M1t[e,E,T] )
    __syncthreads();
    fill_lds(sw, G1p, (16 * TRI_TOTAL) / 4, tid);          // [0, 2560)
    fill_lds(sw + 16 * TRI_TOTAL, M1t, 4096 / 4, tid);     // [2560, 6656)
    __syncthreads();
    float b20[16], b21[16], b22[16], b23[16];
#pragma unroll
    for (int E = 0; E < 16; ++E) { b20[E] = 0.f; b21[E] = 0.f;
                                   b22[E] = 0.f; b23[E] = 0.f; }
    {
#pragma unroll 2
        for (int e = 0; e < 16; ++e) {
            const float ae0 = a[e * NX + x0];
            const float ae1 = a[e * NX + x0 + 256];
            const float ae2 = a[e * NX + x0 + 512];
            const float ae3 = a[e * NX + x0 + 768];
            const float* sg = sw + e * TRI_TOTAL;
            float r0, r1, r2, r3;
            TRIFORM(sg, h0, h1, h2, h3, r0, r1, r2, r3);
            const float pe0 = ae0 * sqrt_act(r0);
            const float pe1 = ae1 * sqrt_act(r1);
            const float pe2 = ae2 * sqrt_act(r2);
            const float pe3 = ae3 * sqrt_act(r3);
            const float* m = sw + 16 * TRI_TOTAL + e * 256;
#pragma unroll
            for (int E = 0; E < 16; ++E) {
                float s0, s1, s2, s3;
                dot4(m + E * 16, h0, h1, h2, h3, s0, s1, s2, s3);
                b20[E] += pe0 * s0;
                b21[E] += pe1 * s1;
                b22[E] += pe2 * s2;
                b23[E] += pe3 * s3;
            }
        }
    }
    // h dead here.

    // ---- memory fence: stop Y-reload CSE keeping X alive (R6 spill cause) ----
    asm volatile("" ::: "memory");
    const float* xr = xb;
    asm volatile("" : "+r"(xr));
    float Y0[16], Y1[16], Y2[16], Y3[16];
#pragma unroll
    for (int t = 0; t < 16; ++t) {
        Y0[t] = xr[t * NC * NX + x0];
        Y1[t] = xr[t * NC * NX + x0 + 256];
        Y2[t] = xr[t * NC * NX + x0 + 512];
        Y3[t] = xr[t * NC * NX + x0 + 768];
    }

    // ======== stage 3: y = sum_T w[T,x] * ( Y^T M2[c,T] b2 ) ========
    __syncthreads();
    fill_lds(sw, M2 + c * 4096, 4096 / 4, tid);
    __syncthreads();
    float y0 = 0.f, y1 = 0.f, y2 = 0.f, y3 = 0.f;
    {
#pragma unroll 2
        for (int T = 0; T < 16; ++T) {
            const float wt0 = w[T * NX + x0];
            const float wt1 = w[T * NX + x0 + 256];
            const float wt2 = w[T * NX + x0 + 512];
            const float wt3 = w[T * NX + x0 + 768];
            const float* m = sw + T * 256;
            float c0 = 0.f, d0 = 0.f, c1 = 0.f, d1 = 0.f;
            float c2 = 0.f, d2 = 0.f, c3 = 0.f, d3 = 0.f;
#pragma unroll
            for (int A = 0; A < 16; ++A) {
                float s0, s1, s2, s3;
                dot4(m + A * 16, b20, b21, b22, b23, s0, s1, s2, s3);
                if (A & 1) { d0 += Y0[A] * s0; d1 += Y1[A] * s1;
                             d2 += Y2[A] * s2; d3 += Y3[A] * s3; }
                else       { c0 += Y0[A] * s0; c1 += Y1[A] * s1;
                             c2 += Y2[A] * s2; c3 += Y3[A] * s3; }
            }
            y0 += wt0 * (c0 + d0);
            y1 += wt1 * (c1 + d1);
            y2 += wt2 * (c2 + d2);
            y3 += wt3 * (c3 + d3);
        }
    }

    // ---- reduce over the block, one atomic per block ----
    float y = (y0 + y1) + (y2 + y3);
#pragma unroll
    for (int off = 32; off > 0; off >>= 1) y += __shfl_down(y, off);
    __shared__ float red[4];
    if ((tid & 63) == 0) red[tid >> 6] = y;
    __syncthreads();
    if (tid == 0) {
        atomicAdd(&out[bp * NC + c], red[0] + red[1] + red[2] + red[3]);
    }
}

extern "C" void kernel_launch(void* const* d_in, const int* in_sizes, int n_in,
                              void* d_out, int out_size, void* d_ws, size_t ws_size,
                              hipStream_t stream) {
    const float* x   = (const float*)d_in[0];
    const float* K0  = (const float*)d_in[1];
    const float* Q0  = (const float*)d_in[2];
    const float* V0  = (const float*)d_in[3];
    const float* K1  = (const float*)d_in[4];
    const float* Q1  = (const float*)d_in[5];
    const float* V1  = (const float*)d_in[6];
    const float* enc = (const float*)d_in[7];
    const float* dec = (const float*)d_in[8];
    const float* a   = (const float*)d_in[9];
    const float* w   = (const float*)d_in[10];
    float* out = (float*)d_out;

    float* G0p = (float*)d_ws;                 // 32*16*160 = 81920 floats
    float* G1p = G0p + NC * 16 * TRI_TOTAL;    // 16*160 = 2560
    float* M1t = G1p + 16 * TRI_TOTAL;         // 4096
    float* M2  = M1t + 4096;                   // 131072
    // total ws: 219648 floats ~= 0.86 MB

    // out must be zeroed every call (harness re-poisons with 0xAA)
    hipMemsetAsync(d_out, 0, (size_t)out_size * sizeof(float), stream);

    g_precompute<<<NC * 16, 256, 0, stream>>>(K0, V0, enc, G0p, NC);
    g_precompute<<<16,      256, 0, stream>>>(K1, V1, enc, G1p, 1);
    m1t_precompute<<<16,  256, 0, stream>>>(Q1, dec, M1t);
    m2_precompute<<<512, 256, 0, stream>>>(Q0, dec, M2);

    const int nblocks = NB * NP * NC * (NX / 1024);  // 512
    site_kernel<<<nblocks, 256, 0, stream>>>(x, a, w, G0p, G1p, M1t, M2, out);
}

// Round 10
// 337.095 us; speedup vs baseline: 2.0807x; 1.0458x over previous
//
#include <hip/hip_runtime.h>
#include <math.h>

// Problem constants (reference: B,P,NTIME,NLATENT,NSPATIAL = 4,2,16,32,2048)
#define NB 4
#define NP 2
#define NT 16
#define NC 32
#define NX 2048

// Exact triangle packing: per e, 136 floats. Row A holds S[A,j], j=0..15-A:
// S[A,0]=G[A,A], S[A,j]=G[A,A+j]+G[A+j,A]. Row offset = A*16 - A(A-1)/2.
#define TRI_N 136

// ---------------------------------------------------------------------------
// Precompute packed-symmetric G for the bilinear stages:
//   G[A,B] = sum_{t,T} enc[e,t,T] * K[t,A,c] * V[T,B,c]  -> exact-136 rows.
// One block per (c,e); cstride==1 => layer 1 (no c axis).
// ---------------------------------------------------------------------------
__global__ void g_precompute(const float* __restrict__ K,
                             const float* __restrict__ V,
                             const float* __restrict__ enc,
                             float* __restrict__ Gp,
                             int cstride) {
    const int bid = blockIdx.x;
    int e, c;
    if (cstride == 1) { e = bid; c = 0; }
    else              { c = bid >> 4; e = bid & 15; }

    __shared__ float sK[256], sV[256], sE[256], sW[256];
    const int tid = threadIdx.x;
    {
        const int t = tid >> 4, A = tid & 15;
        sK[tid] = K[(t * 16 + A) * cstride + c];
        sV[tid] = V[(t * 16 + A) * cstride + c];
        sE[tid] = enc[(e * 16 + t) * 16 + A];
    }
    __syncthreads();
    {   // W[t,B] = sum_T enc[e,t,T] * V[T,B,c]
        const int t = tid >> 4, Bi = tid & 15;
        float acc = 0.f;
#pragma unroll
        for (int T = 0; T < 16; ++T) acc += sE[t * 16 + T] * sV[T * 16 + Bi];
        sW[tid] = acc;
    }
    __syncthreads();
    float gval;
    {   // G[A,B] = sum_t K[t,A,c] * W[t,B]
        const int A = tid >> 4, Bi = tid & 15;
        float acc = 0.f;
#pragma unroll
        for (int t = 0; t < 16; ++t) acc += sK[t * 16 + A] * sW[t * 16 + Bi];
        gval = acc;
    }
    __syncthreads();
    sE[tid] = gval;            // sE := full G tile
    __syncthreads();
    if (tid < TRI_N) {
        int A = 0, off = 0;
        while (A < 15 && tid >= off + (16 - A)) { off += 16 - A; ++A; }
        const int j = tid - off;
        const float v = (j == 0) ? sE[A * 16 + A]
                                 : sE[A * 16 + A + j] + sE[(A + j) * 16 + A];
        Gp[(c * 16 + e) * TRI_N + tid] = v;
    }
}

// M1t[e][E][T] = sum_t Q1[t,T] * dec[e,t,E]   (q1 fused; per-e 256-blocks)
__global__ void m1t_precompute(const float* __restrict__ Q1,
                               const float* __restrict__ dec,
                               float* __restrict__ M1t) {
    const int idx = blockIdx.x * 256 + threadIdx.x;  // 4096
    const int e = idx >> 8, E = (idx >> 4) & 15, T = idx & 15;
    float acc = 0.f;
#pragma unroll
    for (int t = 0; t < 16; ++t)
        acc += Q1[t * 16 + T] * dec[(e * 16 + t) * 16 + E];
    M1t[idx] = acc;
}

// M2[c][T][A][E] = sum_t Q0[t,A,c] * dec[E,t,T]  (q0 fused; per-(c,T) 256-blocks)
__global__ void m2_precompute(const float* __restrict__ Q0,
                              const float* __restrict__ dec,
                              float* __restrict__ M2) {
    const int idx = blockIdx.x * 256 + threadIdx.x;  // 131072
    const int c = idx >> 12, T = (idx >> 8) & 15, A = (idx >> 4) & 15, E = idx & 15;
    float acc = 0.f;
#pragma unroll
    for (int t = 0; t < 16; ++t)
        acc += Q0[(t * 16 + A) * NC + c] * dec[(E * 16 + t) * 16 + T];
    M2[idx] = acc;
}

__device__ __forceinline__ float sqrt_act(float v) {
    return copysignf(sqrtf(fabsf(v)), v);
}

// Broadcast weight float K (compile-time index) out of a lane-distributed
// float4 chunk: lane l holds floats [4l..4l+3]; v_readlane -> SGPR, shared
// by all lanes at zero replication cost. K must be a literal after unroll.
__device__ __forceinline__ float rl(float v, int lane) {
    return __builtin_bit_cast(float,
        __builtin_amdgcn_readlane(__builtin_bit_cast(int, v), lane));
}
#define RLW(CH, K) rl(((const float*)&(CH))[(K) & 3], (K) >> 2)

// Triangular bilinear form, weights via readlane from chunk CH (136 packed
// floats in lanes 0..33). 4 sites = 4 independent FMA chains per row.
#define TRIFORM_RL(CH, V0, V1, V2, V3, R0, R1, R2, R3)                     \
    do {                                                                   \
        float tc0 = 0.f, td0 = 0.f, tc1 = 0.f, td1 = 0.f;                  \
        float tc2 = 0.f, td2 = 0.f, tc3 = 0.f, td3 = 0.f;                  \
        _Pragma("unroll")                                                  \
        for (int A = 0; A < 16; ++A) {                                     \
            const int koff = A * 16 - (A * (A - 1)) / 2;                   \
            float ta0 = 0.f, ta1 = 0.f, ta2 = 0.f, ta3 = 0.f;              \
            _Pragma("unroll")                                              \
            for (int j = 0; j < 16 - A; ++j) {                             \
                const float rw = RLW(CH, koff + j);                        \
                ta0 += rw * V0[A + j];  ta1 += rw * V1[A + j];             \
                ta2 += rw * V2[A + j];  ta3 += rw * V3[A + j];             \
            }                                                              \
            if (A & 1) { td0 += V0[A] * ta0; td1 += V1[A] * ta1;           \
                         td2 += V2[A] * ta2; td3 += V3[A] * ta3; }         \
            else       { tc0 += V0[A] * ta0; tc1 += V1[A] * ta1;           \
                         tc2 += V2[A] * ta2; tc3 += V3[A] * ta3; }         \
        }                                                                  \
        R0 = tc0 + td0;  R1 = tc1 + td1;                                   \
        R2 = tc2 + td2;  R3 = tc3 + td3;                                   \
    } while (0)

// ---------------------------------------------------------------------------
// Main kernel: one thread per FOUR (b,p,c,x) sites (x0 + {0,256,512,768}).
// Weight delivery: lane-distributed global_load_dwordx4 (1 KB = one whole
// 256-float matrix per instruction, L2-resident) + v_readlane broadcast.
// No LDS staging, no barriers, no per-row ds latency: the R4-R9 LDS
// replication wall (64 lanes x 16 B per wave-uniform b128) is bypassed;
// cost moves to the half-idle VALU pipe (~2 cyc/weight, pipelineable).
// Chunk loads double-buffered across e to cover L2 latency.
// grid = NB*NP*NC*(NX/1024) = 512 blocks of 256 = exactly 2/CU.
// ---------------------------------------------------------------------------
__global__ __launch_bounds__(256) void site_kernel(
    const float* __restrict__ x,
    const float* __restrict__ a,
    const float* __restrict__ w,
    const float* __restrict__ G0p,
    const float* __restrict__ G1p,
    const float* __restrict__ M1t,
    const float* __restrict__ M2,
    float* __restrict__ out) {
    const int tid = threadIdx.x;
    const int lane = tid & 63;
    const int bid = blockIdx.x;
    const int xc = bid & 1;
    const int c  = (bid >> 1) & 31;
    const int bp = bid >> 6;              // [0, NB*NP)
    const int x0 = (xc << 10) + tid;      // site s at x0 + s*256
    const float* xb = x + (bp * NT * NC + c) * NX;

    // ---- load all four sites' 16-vectors (coalesced) ----
    float X0[16], X1[16], X2[16], X3[16];
#pragma unroll
    for (int t = 0; t < 16; ++t) {
        X0[t] = xb[t * NC * NX + x0];
        X1[t] = xb[t * NC * NX + x0 + 256];
        X2[t] = xb[t * NC * NX + x0 + 512];
        X3[t] = xb[t * NC * NX + x0 + 768];
    }

    // ======== stage 0: h[e] = sqrt_act( X^T Sym(G0[c,e]) X ) ========
    // e-block = 136 floats = 34 float4; chunk load per e, double-buffered.
    float h0[16], h1[16], h2[16], h3[16];
    {
        const float4* gs = (const float4*)(G0p + c * (16 * TRI_N));
        float4 cur = gs[lane];
#pragma unroll 2
        for (int e = 0; e < 16; ++e) {
            const float4 nxt = gs[((e + 1) & 15) * 34 + lane];
            float r0, r1, r2, r3;
            TRIFORM_RL(cur, X0, X1, X2, X3, r0, r1, r2, r3);
            h0[e] = sqrt_act(r0);
            h1[e] = sqrt_act(r1);
            h2[e] = sqrt_act(r2);
            h3[e] = sqrt_act(r3);
            cur = nxt;
        }
    }
    // X dead here (re-loaded for the final stage).

    // ======== stages 1+2 fused:
    //   p_e = a[e,x] * sqrt_act( h^T Sym(G1[e]) h )
    //   b2[E] += p_e * ( sum_T h_T * M1t[e,E,T] )
    float b20[16], b21[16], b22[16], b23[16];
#pragma unroll
    for (int E = 0; E < 16; ++E) { b20[E] = 0.f; b21[E] = 0.f;
                                   b22[E] = 0.f; b23[E] = 0.f; }
    {
        const float4* gs = (const float4*)G1p;
        const float4* ms = (const float4*)M1t;
        float4 curG = gs[lane];
        float4 curM = ms[lane];
#pragma unroll 1
        for (int e = 0; e < 16; ++e) {
            const float4 nxtG = gs[((e + 1) & 15) * 34 + lane];
            const float4 nxtM = ms[((e + 1) & 15) * 64 + lane];
            const float ae0 = a[e * NX + x0];
            const float ae1 = a[e * NX + x0 + 256];
            const float ae2 = a[e * NX + x0 + 512];
            const float ae3 = a[e * NX + x0 + 768];
            float r0, r1, r2, r3;
            TRIFORM_RL(curG, h0, h1, h2, h3, r0, r1, r2, r3);
            const float pe0 = ae0 * sqrt_act(r0);
            const float pe1 = ae1 * sqrt_act(r1);
            const float pe2 = ae2 * sqrt_act(r2);
            const float pe3 = ae3 * sqrt_act(r3);
#pragma unroll
            for (int E = 0; E < 16; ++E) {
                float s0 = 0.f, s1 = 0.f, s2 = 0.f, s3 = 0.f;
#pragma unroll
                for (int T = 0; T < 16; ++T) {
                    const float rw = RLW(curM, E * 16 + T);
                    s0 += rw * h0[T];  s1 += rw * h1[T];
                    s2 += rw * h2[T];  s3 += rw * h3[T];
                }
                b20[E] += pe0 * s0;
                b21[E] += pe1 * s1;
                b22[E] += pe2 * s2;
                b23[E] += pe3 * s3;
            }
            curG = nxtG;
            curM = nxtM;
        }
    }
    // h dead here.

    // ---- memory fence: stop Y-reload CSE keeping X alive (R6 spill cause) ----
    asm volatile("" ::: "memory");
    const float* xr = xb;
    asm volatile("" : "+r"(xr));
    float Y0[16], Y1[16], Y2[16], Y3[16];
#pragma unroll
    for (int t = 0; t < 16; ++t) {
        Y0[t] = xr[t * NC * NX + x0];
        Y1[t] = xr[t * NC * NX + x0 + 256];
        Y2[t] = xr[t * NC * NX + x0 + 512];
        Y3[t] = xr[t * NC * NX + x0 + 768];
    }

    // ======== stage 3: y = sum_T w[T,x] * ( Y^T M2[c,T] b2 ) ========
    float y0 = 0.f, y1 = 0.f, y2 = 0.f, y3 = 0.f;
    {
        const float4* ms = (const float4*)(M2 + c * 4096);
        float4 cur = ms[lane];
#pragma unroll 1
        for (int T = 0; T < 16; ++T) {
            const float4 nxt = ms[((T + 1) & 15) * 64 + lane];
            const float wt0 = w[T * NX + x0];
            const float wt1 = w[T * NX + x0 + 256];
            const float wt2 = w[T * NX + x0 + 512];
            const float wt3 = w[T * NX + x0 + 768];
            float c0 = 0.f, d0 = 0.f, c1 = 0.f, d1 = 0.f;
            float c2 = 0.f, d2 = 0.f, c3 = 0.f, d3 = 0.f;
#pragma unroll
            for (int A = 0; A < 16; ++A) {
                float s0 = 0.f, s1 = 0.f, s2 = 0.f, s3 = 0.f;
#pragma unroll
                for (int E = 0; E < 16; ++E) {
                    const float rw = RLW(cur, A * 16 + E);
                    s0 += rw * b20[E];  s1 += rw * b21[E];
                    s2 += rw * b22[E];  s3 += rw * b23[E];
                }
                if (A & 1) { d0 += Y0[A] * s0; d1 += Y1[A] * s1;
                             d2 += Y2[A] * s2; d3 += Y3[A] * s3; }
                else       { c0 += Y0[A] * s0; c1 += Y1[A] * s1;
                             c2 += Y2[A] * s2; c3 += Y3[A] * s3; }
            }
            y0 += wt0 * (c0 + d0);
            y1 += wt1 * (c1 + d1);
            y2 += wt2 * (c2 + d2);
            y3 += wt3 * (c3 + d3);
            cur = nxt;
        }
    }

    // ---- reduce over the block, one atomic per block ----
    float y = (y0 + y1) + (y2 + y3);
#pragma unroll
    for (int off = 32; off > 0; off >>= 1) y += __shfl_down(y, off);
    __shared__ float red[4];
    if ((tid & 63) == 0) red[tid >> 6] = y;
    __syncthreads();
    if (tid == 0) {
        atomicAdd(&out[bp * NC + c], red[0] + red[1] + red[2] + red[3]);
    }
}

extern "C" void kernel_launch(void* const* d_in, const int* in_sizes, int n_in,
                              void* d_out, int out_size, void* d_ws, size_t ws_size,
                              hipStream_t stream) {
    const float* x   = (const float*)d_in[0];
    const float* K0  = (const float*)d_in[1];
    const float* Q0  = (const float*)d_in[2];
    const float* V0  = (const float*)d_in[3];
    const float* K1  = (const float*)d_in[4];
    const float* Q1  = (const float*)d_in[5];
    const float* V1  = (const float*)d_in[6];
    const float* enc = (const float*)d_in[7];
    const float* dec = (const float*)d_in[8];
    const float* a   = (const float*)d_in[9];
    const float* w   = (const float*)d_in[10];
    float* out = (float*)d_out;

    float* G0p = (float*)d_ws;                // 32*16*136 = 69632 floats
    float* G1p = G0p + NC * 16 * TRI_N;       // 16*136 = 2176
    float* M1t = G1p + 16 * TRI_N;            // 4096
    float* M2  = M1t + 4096;                  // 131072
    // total ws: 206976 floats ~= 0.83 MB (plus harmless prefetch overread)

    // out must be zeroed every call (harness re-poisons with 0xAA)
    hipMemsetAsync(d_out, 0, (size_t)out_size * sizeof(float), stream);

    g_precompute<<<NC * 16, 256, 0, stream>>>(K0, V0, enc, G0p, NC);
    g_precompute<<<16,      256, 0, stream>>>(K1, V1, enc, G1p, 1);
    m1t_precompute<<<16,  256, 0, stream>>>(Q1, dec, M1t);
    m2_precompute<<<512, 256, 0, stream>>>(Q0, dec, M2);

    const int nblocks = NB * NP * NC * (NX / 1024);  // 512
    site_kernel<<<nblocks, 256, 0, stream>>>(x, a, w, G0p, G1p, M1t, M2, out);
}

// Round 11
// 310.568 us; speedup vs baseline: 2.2584x; 1.0854x over previous
//
#include <hip/hip_runtime.h>
#include <math.h>

// Problem constants (reference: B,P,NTIME,NLATENT,NSPATIAL = 4,2,16,32,2048)
#define NB 4
#define NP 2
#define NT 16
#define NC 32
#define NX 2048

// Exact triangle packing: per e, 136 floats. Row A holds S[A,j], j=0..15-A:
// S[A,0]=G[A,A], S[A,j]=G[A,A+j]+G[A+j,A]. Row offset = A*16 - A(A-1)/2.
#define TRI_N 136

// ---------------------------------------------------------------------------
// Precompute packed-symmetric G for the bilinear stages:
//   G[A,B] = sum_{t,T} enc[e,t,T] * K[t,A,c] * V[T,B,c]  -> exact-136 rows.
// One block per (c,e); cstride==1 => layer 1 (no c axis).
// ---------------------------------------------------------------------------
__global__ void g_precompute(const float* __restrict__ K,
                             const float* __restrict__ V,
                             const float* __restrict__ enc,
                             float* __restrict__ Gp,
                             int cstride) {
    const int bid = blockIdx.x;
    int e, c;
    if (cstride == 1) { e = bid; c = 0; }
    else              { c = bid >> 4; e = bid & 15; }

    __shared__ float sK[256], sV[256], sE[256], sW[256];
    const int tid = threadIdx.x;
    {
        const int t = tid >> 4, A = tid & 15;
        sK[tid] = K[(t * 16 + A) * cstride + c];
        sV[tid] = V[(t * 16 + A) * cstride + c];
        sE[tid] = enc[(e * 16 + t) * 16 + A];
    }
    __syncthreads();
    {   // W[t,B] = sum_T enc[e,t,T] * V[T,B,c]
        const int t = tid >> 4, Bi = tid & 15;
        float acc = 0.f;
#pragma unroll
        for (int T = 0; T < 16; ++T) acc += sE[t * 16 + T] * sV[T * 16 + Bi];
        sW[tid] = acc;
    }
    __syncthreads();
    float gval;
    {   // G[A,B] = sum_t K[t,A,c] * W[t,B]
        const int A = tid >> 4, Bi = tid & 15;
        float acc = 0.f;
#pragma unroll
        for (int t = 0; t < 16; ++t) acc += sK[t * 16 + A] * sW[t * 16 + Bi];
        gval = acc;
    }
    __syncthreads();
    sE[tid] = gval;            // sE := full G tile
    __syncthreads();
    if (tid < TRI_N) {
        int A = 0, off = 0;
        while (A < 15 && tid >= off + (16 - A)) { off += 16 - A; ++A; }
        const int j = tid - off;
        const float v = (j == 0) ? sE[A * 16 + A]
                                 : sE[A * 16 + A + j] + sE[(A + j) * 16 + A];
        Gp[(c * 16 + e) * TRI_N + tid] = v;
    }
}

// M1t[e][E][T] = sum_t Q1[t,T] * dec[e,t,E]   (q1 fused; per-e 256-blocks)
__global__ void m1t_precompute(const float* __restrict__ Q1,
                               const float* __restrict__ dec,
                               float* __restrict__ M1t) {
    const int idx = blockIdx.x * 256 + threadIdx.x;  // 4096
    const int e = idx >> 8, E = (idx >> 4) & 15, T = idx & 15;
    float acc = 0.f;
#pragma unroll
    for (int t = 0; t < 16; ++t)
        acc += Q1[t * 16 + T] * dec[(e * 16 + t) * 16 + E];
    M1t[idx] = acc;
}

// M2[c][T][A][E] = sum_t Q0[t,A,c] * dec[E,t,T]  (q0 fused; per-(c,T) 256-blocks)
__global__ void m2_precompute(const float* __restrict__ Q0,
                              const float* __restrict__ dec,
                              float* __restrict__ M2) {
    const int idx = blockIdx.x * 256 + threadIdx.x;  // 131072
    const int c = idx >> 12, T = (idx >> 8) & 15, A = (idx >> 4) & 15, E = idx & 15;
    float acc = 0.f;
#pragma unroll
    for (int t = 0; t < 16; ++t)
        acc += Q0[(t * 16 + A) * NC + c] * dec[(E * 16 + t) * 16 + T];
    M2[idx] = acc;
}

__device__ __forceinline__ float sqrt_act(float v) {
    return copysignf(sqrtf(fabsf(v)), v);
}

// Broadcast weight float K (compile-time index) out of a lane-distributed
// float4 chunk: lane l holds floats [4l..4l+3]; v_readlane -> SGPR, shared
// by all lanes at zero replication cost. K must be a literal after unroll.
__device__ __forceinline__ float rl(float v, int lane) {
    return __builtin_bit_cast(float,
        __builtin_amdgcn_readlane(__builtin_bit_cast(int, v), lane));
}
#define RLW(CH, K) rl(((const float*)&(CH))[(K) & 3], (K) >> 2)

// Triangular bilinear form, weights via readlane from chunk CH (136 packed
// floats in lanes 0..33). TWO sites = 2 independent FMA chains per row
// (plus even/odd outer split = 4 chains total).
#define TRIFORM_RL2(CH, V0, V1, R0, R1)                                    \
    do {                                                                   \
        float tc0 = 0.f, td0 = 0.f, tc1 = 0.f, td1 = 0.f;                  \
        _Pragma("unroll")                                                  \
        for (int A = 0; A < 16; ++A) {                                     \
            const int koff = A * 16 - (A * (A - 1)) / 2;                   \
            float ta0 = 0.f, ta1 = 0.f;                                    \
            _Pragma("unroll")                                              \
            for (int j = 0; j < 16 - A; ++j) {                             \
                const float rw = RLW(CH, koff + j);                        \
                ta0 += rw * V0[A + j];  ta1 += rw * V1[A + j];             \
            }                                                              \
            if (A & 1) { td0 += V0[A] * ta0; td1 += V1[A] * ta1; }         \
            else       { tc0 += V0[A] * ta0; tc1 += V1[A] * ta1; }         \
        }                                                                  \
        R0 = tc0 + td0;  R1 = tc1 + td1;                                   \
    } while (0)

// ---------------------------------------------------------------------------
// Main kernel: one thread per TWO (b,p,c,x) sites (x0, x0+256).
// Weight delivery: lane-distributed global_load_dwordx4 + v_readlane
// broadcast (R10 mechanism — no LDS, no barriers, no SMEM lgkmcnt drain).
// R10 post-mortem: at R=4 only 2 waves/SIMD -> ~50% issue efficiency,
// latency-bound. This round trades per-wave work for TLP: R=2 doubles the
// wave count (1024 blocks -> 3-4 waves/SIMD at VGPR<=~170/128), which is
// what covers the readlane->FMA and chain latencies.
// grid = NB*NP*NC*(NX/512) = 1024 blocks of 256 = 4 blocks/CU target.
// bid bits: [1:0]=x-chunk, [6:2]=c, [9:7]=bp
// ---------------------------------------------------------------------------
__global__ __launch_bounds__(256) void site_kernel(
    const float* __restrict__ x,
    const float* __restrict__ a,
    const float* __restrict__ w,
    const float* __restrict__ G0p,
    const float* __restrict__ G1p,
    const float* __restrict__ M1t,
    const float* __restrict__ M2,
    float* __restrict__ out) {
    const int tid = threadIdx.x;
    const int lane = tid & 63;
    const int bid = blockIdx.x;
    const int xc = bid & 3;
    const int c  = (bid >> 2) & 31;
    const int bp = bid >> 7;              // [0, NB*NP)
    const int x0 = (xc << 9) + tid;       // site 0; site 1 at x0+256
    const float* xb = x + (bp * NT * NC + c) * NX;

    // ---- load both sites' 16-vectors (coalesced) ----
    float X0[16], X1[16];
#pragma unroll
    for (int t = 0; t < 16; ++t) {
        X0[t] = xb[t * NC * NX + x0];
        X1[t] = xb[t * NC * NX + x0 + 256];
    }

    // ======== stage 0: h[e] = sqrt_act( X^T Sym(G0[c,e]) X ) ========
    // e-block = 136 floats = 34 float4; chunk load per e, double-buffered.
    float h0[16], h1[16];
    {
        const float4* gs = (const float4*)(G0p + c * (16 * TRI_N));
        float4 cur = gs[lane];
#pragma unroll 2
        for (int e = 0; e < 16; ++e) {
            const float4 nxt = gs[((e + 1) & 15) * 34 + lane];
            float r0, r1;
            TRIFORM_RL2(cur, X0, X1, r0, r1);
            h0[e] = sqrt_act(r0);
            h1[e] = sqrt_act(r1);
            cur = nxt;
        }
    }
    // X dead here (re-loaded for the final stage).

    // ======== stages 1+2 fused:
    //   p_e = a[e,x] * sqrt_act( h^T Sym(G1[e]) h )
    //   b2[E] += p_e * ( sum_T h_T * M1t[e,E,T] )
    float b20[16], b21[16];
#pragma unroll
    for (int E = 0; E < 16; ++E) { b20[E] = 0.f; b21[E] = 0.f; }
    {
        const float4* gs = (const float4*)G1p;
        const float4* ms = (const float4*)M1t;
        float4 curG = gs[lane];
        float4 curM = ms[lane];
#pragma unroll 1
        for (int e = 0; e < 16; ++e) {
            const float4 nxtG = gs[((e + 1) & 15) * 34 + lane];
            const float4 nxtM = ms[((e + 1) & 15) * 64 + lane];
            const float ae0 = a[e * NX + x0];
            const float ae1 = a[e * NX + x0 + 256];
            float r0, r1;
            TRIFORM_RL2(curG, h0, h1, r0, r1);
            const float pe0 = ae0 * sqrt_act(r0);
            const float pe1 = ae1 * sqrt_act(r1);
#pragma unroll
            for (int E = 0; E < 16; ++E) {
                float s0 = 0.f, s1 = 0.f;
#pragma unroll
                for (int T = 0; T < 16; ++T) {
                    const float rw = RLW(curM, E * 16 + T);
                    s0 += rw * h0[T];  s1 += rw * h1[T];
                }
                b20[E] += pe0 * s0;
                b21[E] += pe1 * s1;
            }
            curG = nxtG;
            curM = nxtM;
        }
    }
    // h dead here.

    // ---- memory fence: stop Y-reload CSE keeping X alive (R6 spill cause) ----
    asm volatile("" ::: "memory");
    const float* xr = xb;
    asm volatile("" : "+r"(xr));
    float Y0[16], Y1[16];
#pragma unroll
    for (int t = 0; t < 16; ++t) {
        Y0[t] = xr[t * NC * NX + x0];
        Y1[t] = xr[t * NC * NX + x0 + 256];
    }

    // ======== stage 3: y = sum_T w[T,x] * ( Y^T M2[c,T] b2 ) ========
    float y0 = 0.f, y1 = 0.f;
    {
        const float4* ms = (const float4*)(M2 + c * 4096);
        float4 cur = ms[lane];
#pragma unroll 1
        for (int T = 0; T < 16; ++T) {
            const float4 nxt = ms[((T + 1) & 15) * 64 + lane];
            const float wt0 = w[T * NX + x0];
            const float wt1 = w[T * NX + x0 + 256];
            float c0 = 0.f, d0 = 0.f, c1 = 0.f, d1 = 0.f;
#pragma unroll
            for (int A = 0; A < 16; ++A) {
                float s0 = 0.f, s1 = 0.f;
#pragma unroll
                for (int E = 0; E < 16; ++E) {
                    const float rw = RLW(cur, A * 16 + E);
                    s0 += rw * b20[E];  s1 += rw * b21[E];
                }
                if (A & 1) { d0 += Y0[A] * s0; d1 += Y1[A] * s1; }
                else       { c0 += Y0[A] * s0; c1 += Y1[A] * s1; }
            }
            y0 += wt0 * (c0 + d0);
            y1 += wt1 * (c1 + d1);
            cur = nxt;
        }
    }

    // ---- reduce over the block, one atomic per block ----
    float y = y0 + y1;
#pragma unroll
    for (int off = 32; off > 0; off >>= 1) y += __shfl_down(y, off);
    __shared__ float red[4];
    if ((tid & 63) == 0) red[tid >> 6] = y;
    __syncthreads();
    if (tid == 0) {
        atomicAdd(&out[bp * NC + c], red[0] + red[1] + red[2] + red[3]);
    }
}

extern "C" void kernel_launch(void* const* d_in, const int* in_sizes, int n_in,
                              void* d_out, int out_size, void* d_ws, size_t ws_size,
                              hipStream_t stream) {
    const float* x   = (const float*)d_in[0];
    const float* K0  = (const float*)d_in[1];
    const float* Q0  = (const float*)d_in[2];
    const float* V0  = (const float*)d_in[3];
    const float* K1  = (const float*)d_in[4];
    const float* Q1  = (const float*)d_in[5];
    const float* V1  = (const float*)d_in[6];
    const float* enc = (const float*)d_in[7];
    const float* dec = (const float*)d_in[8];
    const float* a   = (const float*)d_in[9];
    const float* w   = (const float*)d_in[10];
    float* out = (float*)d_out;

    float* G0p = (float*)d_ws;                // 32*16*136 = 69632 floats
    float* G1p = G0p + NC * 16 * TRI_N;       // 16*136 = 2176
    float* M1t = G1p + 16 * TRI_N;            // 4096
    float* M2  = M1t + 4096;                  // 131072
    // total ws: 206976 floats ~= 0.83 MB (plus harmless prefetch overread)

    // out must be zeroed every call (harness re-poisons with 0xAA)
    hipMemsetAsync(d_out, 0, (size_t)out_size * sizeof(float), stream);

    g_precompute<<<NC * 16, 256, 0, stream>>>(K0, V0, enc, G0p, NC);
    g_precompute<<<16,      256, 0, stream>>>(K1, V1, enc, G1p, 1);
    m1t_precompute<<<16,  256, 0, stream>>>(Q1, dec, M1t);
    m2_precompute<<<512, 256, 0, stream>>>(Q0, dec, M2);

    const int nblocks = NB * NP * NC * (NX / 512);  // 1024
    site_kernel<<<nblocks, 256, 0, stream>>>(x, a, w, G0p, G1p, M1t, M2, out);
}